// Round 6
// baseline (29.024 us; speedup 1.0000x reference)
//
#include <hip/hip_runtime.h>

#define IMG 512
#define CH_STRIDE (IMG * IMG)   // 262144

__device__ __forceinline__ float4 fmin4(float4 a, float4 b) {
    float4 r;
    r.x = fminf(a.x, b.x); r.y = fminf(a.y, b.y);
    r.z = fminf(a.z, b.z); r.w = fminf(a.w, b.w);
    return r;
}

// hgroup(u0..u4): outputs k=0..3 -> min(flat[k+1 .. k+15]) over the 20 floats
__device__ __forceinline__ float4 hgroup(float4 u0, float4 u1, float4 u2,
                                         float4 u3, float4 u4) {
    float4 m4 = fmin4(u1, fmin4(u2, u3));
    float common = fminf(fminf(m4.x, m4.y), fminf(m4.z, m4.w));
    float pz = fminf(u0.z, u0.w);
    float sz = fminf(u4.x, u4.y);
    float4 o;
    o.x = fminf(common, fminf(u0.y, pz));
    o.y = fminf(common, fminf(pz, u4.x));
    o.z = fminf(common, fminf(u0.w, sz));
    o.w = fminf(common, fminf(sz, u4.z));
    return o;
}

// ---------------- Kernel 1: channel-min + horizontal 15-min ----------------
// One thread per (img, row, 16-col group): 24 vector loads, 16 outputs.
__global__ __launch_bounds__(256)
void hpass(const float* __restrict__ x, float* __restrict__ hmin) {
    int idx = blockIdx.x * 256 + threadIdx.x;   // 16*512*32 = 262144
    int t   = idx & 31;            // 16-col group: out cols 16t..16t+15
    int rr  = idx >> 5;
    int row = rr & 511;
    int img = rr >> 9;

    int bb = 16 * t - 8;
    bb = bb < 0 ? 0 : (bb > IMG - 32 ? IMG - 32 : bb);   // only t=0, t=31 clamp
    const float* p = x + img * 3 * CH_STRIDE + row * IMG + bb;

    // channel 0 loads, then fold in channels 1 and 2 (caps live registers)
    float4 v0 = *(const float4*)(p +  0), v1 = *(const float4*)(p +  4),
           v2 = *(const float4*)(p +  8), v3 = *(const float4*)(p + 12),
           v4 = *(const float4*)(p + 16), v5 = *(const float4*)(p + 20),
           v6 = *(const float4*)(p + 24), v7 = *(const float4*)(p + 28);
    const float* q = p + CH_STRIDE;
    v0 = fmin4(v0, *(const float4*)(q +  0));
    v1 = fmin4(v1, *(const float4*)(q +  4));
    v2 = fmin4(v2, *(const float4*)(q +  8));
    v3 = fmin4(v3, *(const float4*)(q + 12));
    v4 = fmin4(v4, *(const float4*)(q + 16));
    v5 = fmin4(v5, *(const float4*)(q + 20));
    v6 = fmin4(v6, *(const float4*)(q + 24));
    v7 = fmin4(v7, *(const float4*)(q + 28));
    const float* s2 = p + 2 * CH_STRIDE;
    v0 = fmin4(v0, *(const float4*)(s2 +  0));
    v1 = fmin4(v1, *(const float4*)(s2 +  4));
    v2 = fmin4(v2, *(const float4*)(s2 +  8));
    v3 = fmin4(v3, *(const float4*)(s2 + 12));
    v4 = fmin4(v4, *(const float4*)(s2 + 16));
    v5 = fmin4(v5, *(const float4*)(s2 + 20));
    v6 = fmin4(v6, *(const float4*)(s2 + 24));
    v7 = fmin4(v7, *(const float4*)(s2 + 28));

    float4 o0, o1, o2, o3;
    if (t == 0) {
        // bb=0: out c (c<8) = prefix-min lm[0..c+7]; c=8..15 ordinary windows
        float pm7  = fminf(fminf(fminf(v0.x, v0.y), fminf(v0.z, v0.w)),
                           fminf(fminf(v1.x, v1.y), fminf(v1.z, v1.w)));
        float pm8  = fminf(pm7,  v2.x);
        float pm9  = fminf(pm8,  v2.y);
        float pm10 = fminf(pm9,  v2.z);
        float pm11 = fminf(pm10, v2.w);
        float pm12 = fminf(pm11, v3.x);
        float pm13 = fminf(pm12, v3.y);
        float pm14 = fminf(pm13, v3.z);
        o0 = make_float4(pm7,  pm8,  pm9,  pm10);
        o1 = make_float4(pm11, pm12, pm13, pm14);
        o2 = hgroup(v0, v1, v2, v3, v4);   // c=8..11: windows lm[1..15]..lm[4..18]
        o3 = hgroup(v1, v2, v3, v4, v5);   // c=12..15
    } else if (t == 31) {
        // bb=480 (shift 8): c=496..503 ordinary; c=504..511 = suffix-min lm[c-487..31]
        o0 = hgroup(v2, v3, v4, v5, v6);   // c=496..499: window lm[i+9..i+23]
        o1 = hgroup(v3, v4, v5, v6, v7);   // c=500..503
        float sm24 = fminf(fminf(fminf(v6.x, v6.y), fminf(v6.z, v6.w)),
                           fminf(fminf(v7.x, v7.y), fminf(v7.z, v7.w)));
        float sm23 = fminf(sm24, v5.w);
        float sm22 = fminf(sm23, v5.z);
        float sm21 = fminf(sm22, v5.y);
        float sm20 = fminf(sm21, v5.x);
        float sm19 = fminf(sm20, v4.w);
        float sm18 = fminf(sm19, v4.z);
        float sm17 = fminf(sm18, v4.y);
        o2 = make_float4(sm17, sm18, sm19, sm20);  // c=504..507
        o3 = make_float4(sm21, sm22, sm23, sm24);  // c=508..511
    } else {
        // interior: out 16t+4g+k = min lm[4g+k+1 .. 4g+k+15]
        o0 = hgroup(v0, v1, v2, v3, v4);
        o1 = hgroup(v1, v2, v3, v4, v5);
        o2 = hgroup(v2, v3, v4, v5, v6);
        o3 = hgroup(v3, v4, v5, v6, v7);
    }

    float* op = hmin + img * CH_STRIDE + row * IMG + 16 * t;
    *(float4*)(op)      = o0;
    *(float4*)(op +  4) = o1;
    *(float4*)(op +  8) = o2;
    *(float4*)(op + 12) = o3;
}

// ---------------- Kernel 2: vertical 15-min, van Herk period 16 ------------
// (byte-for-byte Round-4 version — part of the best measured config)
__global__ __launch_bounds__(256)
void vpass(const float* __restrict__ hmin, float* __restrict__ out) {
    int idx = blockIdx.x * 256 + threadIdx.x;   // 16*32*128 = 65,536
    int c   = idx & 127;
    int ss  = idx >> 7;
    int s   = ss & 31;
    int img = ss >> 5;

    const float* base = hmin + img * CH_STRIDE + 4 * c;
    int r0 = 16 * s - 8;

    float4 A[16], B[16];
    #pragma unroll
    for (int j = 0; j < 16; ++j) {       // rows r0 .. r0+15 (reflect low)
        int r = r0 + j;
        r = r < 0 ? -r : r;
        A[j] = *(const float4*)(base + r * IMG);
    }
    #pragma unroll
    for (int j = 0; j < 16; ++j) {       // rows r0+16 .. r0+31 (reflect high)
        int r = r0 + 16 + j;
        r = r > IMG - 1 ? 2 * (IMG - 1) - r : r;
        B[j] = *(const float4*)(base + r * IMG);
    }

    #pragma unroll
    for (int j = 14; j >= 0; --j) A[j] = fmin4(A[j], A[j + 1]);

    float* ob = out + img * CH_STRIDE + (16 * s) * IMG + 4 * c;
    *(float4*)(ob) = A[1];
    float4 pr = B[0];
    #pragma unroll
    for (int k = 1; k <= 14; ++k) {
        *(float4*)(ob + k * IMG) = fmin4(A[k + 1], pr);
        pr = fmin4(pr, B[k]);
    }
    *(float4*)(ob + 15 * IMG) = pr;
}

// ---------------- Fallback fused kernel (round-3, known-correct) -----------
#define KER    15
#define PAD    7
#define TILE_W 64
#define TILE_H 64
#define SH     (TILE_H + 2 * PAD)
#define SW2    80
#define NTHREADS 512

__device__ __forceinline__ int reflect_idx(int i) {
    i = i < 0 ? -i : i;
    return i > IMG - 1 ? 2 * (IMG - 1) - i : i;
}

__global__ __launch_bounds__(NTHREADS, 8)
void dark_channel_fused(const float* __restrict__ x, float* __restrict__ out) {
    __shared__ float smin[SH][SW2];
    const int tid = threadIdx.x;
    const int bx  = blockIdx.x;
    const int by  = blockIdx.y;
    const int b   = blockIdx.z;
    const int base  = b * 3 * CH_STRIDE;
    const int row0  = by * TILE_H - PAD;
    const int col0a = bx * TILE_W - (PAD + 1);

    #pragma unroll
    for (int it = 0; it < 4; ++it) {
        int idx = tid + it * NTHREADS;
        if (idx < SH * 20) {
            int r  = idx / 20;
            int c4 = idx - r * 20;
            int gr = reflect_idx(row0 + r);
            int gc = col0a + 4 * c4;
            float4 v;
            if (gc >= 0 && gc <= IMG - 4) {
                int off = base + gr * IMG + gc;
                float4 a  = *(const float4*)(x + off);
                float4 bb = *(const float4*)(x + off + CH_STRIDE);
                float4 cc = *(const float4*)(x + off + 2 * CH_STRIDE);
                v = fmin4(fmin4(a, bb), cc);
            } else {
                #pragma unroll
                for (int j = 0; j < 4; ++j) {
                    int g   = reflect_idx(gc + j);
                    int off = base + gr * IMG + g;
                    float m = fminf(fminf(x[off], x[off + CH_STRIDE]), x[off + 2 * CH_STRIDE]);
                    if (j == 0) v.x = m; else if (j == 1) v.y = m;
                    else if (j == 2) v.z = m; else v.w = m;
                }
            }
            *(float4*)&smin[r][4 * c4] = v;
        }
    }
    __syncthreads();

    float4 h0, h1, h2;
    #pragma unroll
    for (int it = 0; it < 3; ++it) {
        int idx = tid + it * NTHREADS;
        if (idx < SH * 16) {
            int r  = idx >> 4;
            int c4 = idx & 15;
            const float* rowp = &smin[r][4 * c4];
            float4 v0 = *(const float4*)(rowp);
            float4 v1 = *(const float4*)(rowp + 4);
            float4 v2 = *(const float4*)(rowp + 8);
            float4 v3 = *(const float4*)(rowp + 12);
            float4 v4 = *(const float4*)(rowp + 16);
            float4 o  = hgroup(v0, v1, v2, v3, v4);
            if (it == 0) h0 = o; else if (it == 1) h1 = o; else h2 = o;
        }
    }
    __syncthreads();

    #pragma unroll
    for (int it = 0; it < 3; ++it) {
        int idx = tid + it * NTHREADS;
        if (idx < SH * 16) {
            int r  = idx >> 4;
            int c4 = idx & 15;
            float4 o = (it == 0) ? h0 : (it == 1) ? h1 : h2;
            *(float4*)&smin[r][4 * c4] = o;
        }
    }
    __syncthreads();

    #pragma unroll
    for (int it = 0; it < 2; ++it) {
        int idx = tid + it * NTHREADS;
        int rg = idx >> 6;
        int c  = idx & 63;
        int rb = rg * 4;
        float w0  = smin[rb +  0][c], w1  = smin[rb +  1][c], w2  = smin[rb +  2][c];
        float w3  = smin[rb +  3][c], w4  = smin[rb +  4][c], w5  = smin[rb +  5][c];
        float w6  = smin[rb +  6][c], w7  = smin[rb +  7][c], w8  = smin[rb +  8][c];
        float w9  = smin[rb +  9][c], w10 = smin[rb + 10][c], w11 = smin[rb + 11][c];
        float w12 = smin[rb + 12][c], w13 = smin[rb + 13][c], w14 = smin[rb + 14][c];
        float w15 = smin[rb + 15][c], w16 = smin[rb + 16][c], w17 = smin[rb + 17][c];
        float ca = fminf(fminf(w3, w4),  fminf(w5, w6));
        float cb = fminf(fminf(w7, w8),  fminf(w9, w10));
        float cc = fminf(fminf(w11, w12), fminf(w13, w14));
        float common = fminf(ca, fminf(cb, cc));
        float p = fminf(w1, w2);
        float s = fminf(w15, w16);
        int obase = b * CH_STRIDE + (by * TILE_H + rb) * IMG + bx * TILE_W + c;
        out[obase]           = fminf(common, fminf(w0, p));
        out[obase + IMG]     = fminf(common, fminf(p, w15));
        out[obase + 2 * IMG] = fminf(common, fminf(w2, s));
        out[obase + 3 * IMG] = fminf(common, fminf(s, w17));
    }
}

extern "C" void kernel_launch(void* const* d_in, const int* in_sizes, int n_in,
                              void* d_out, int out_size, void* d_ws, size_t ws_size,
                              hipStream_t stream) {
    const float* x = (const float*)d_in[0];
    float* out = (float*)d_out;
    const size_t need = (size_t)16 * CH_STRIDE * sizeof(float);  // 16.8 MB
    if (ws_size >= need && d_ws != nullptr) {
        float* hm = (float*)d_ws;
        hpass<<<dim3(16 * 512 * 32 / 256), dim3(256), 0, stream>>>(x, hm);
        vpass<<<dim3(16 * 32 * 128 / 256),  dim3(256), 0, stream>>>(hm, out);
    } else {
        dim3 grid(IMG / TILE_W, IMG / TILE_H, 16);
        dark_channel_fused<<<grid, dim3(NTHREADS), 0, stream>>>(x, out);
    }
}

// Round 7
// 24.929 us; speedup vs baseline: 1.1643x; 1.1643x over previous
//
#include <hip/hip_runtime.h>

#define IMG 512
#define CH_STRIDE (IMG * IMG)   // 262144

__device__ __forceinline__ float4 fmin4(float4 a, float4 b) {
    float4 r;
    r.x = fminf(a.x, b.x); r.y = fminf(a.y, b.y);
    r.z = fminf(a.z, b.z); r.w = fminf(a.w, b.w);
    return r;
}

__device__ __forceinline__ float2 fmin2(float2 a, float2 b) {
    float2 r;
    r.x = fminf(a.x, b.x); r.y = fminf(a.y, b.y);
    return r;
}

// hgroup(u0..u4): outputs k=0..3 -> min(flat[k+1 .. k+15]) over the 20 floats
__device__ __forceinline__ float4 hgroup(float4 u0, float4 u1, float4 u2,
                                         float4 u3, float4 u4) {
    float4 m4 = fmin4(u1, fmin4(u2, u3));
    float common = fminf(fminf(m4.x, m4.y), fminf(m4.z, m4.w));
    float pz = fminf(u0.z, u0.w);
    float sz = fminf(u4.x, u4.y);
    float4 o;
    o.x = fminf(common, fminf(u0.y, pz));
    o.y = fminf(common, fminf(pz, u4.x));
    o.z = fminf(common, fminf(u0.w, sz));
    o.w = fminf(common, fminf(sz, u4.z));
    return o;
}

// ---------------- Kernel 1: channel-min + horizontal 15-min ----------------
// (Round-4 version, byte-for-byte — best measured. 4 cols/thread, coalesced.)
__global__ __launch_bounds__(256)
void hpass(const float* __restrict__ x, float* __restrict__ hmin) {
    int idx = blockIdx.x * 256 + threadIdx.x;   // 16*512*128 = 1,048,576
    int t   = idx & 127;           // 4-col group, out cols 4t..4t+3
    int rr  = idx >> 7;
    int row = rr & 511;
    int img = rr >> 9;

    int bb = 4 * t - 8;
    bb = bb < 0 ? 0 : (bb > IMG - 20 ? IMG - 20 : bb);   // clamped aligned base
    const float* p = x + img * 3 * CH_STRIDE + row * IMG + bb;

    float4 a0 = *(const float4*)(p +  0), a1 = *(const float4*)(p +  4),
           a2 = *(const float4*)(p +  8), a3 = *(const float4*)(p + 12),
           a4 = *(const float4*)(p + 16);
    const float* q = p + CH_STRIDE;
    float4 b0 = *(const float4*)(q +  0), b1 = *(const float4*)(q +  4),
           b2 = *(const float4*)(q +  8), b3 = *(const float4*)(q + 12),
           b4 = *(const float4*)(q + 16);
    const float* s2 = p + 2 * CH_STRIDE;
    float4 c0 = *(const float4*)(s2 +  0), c1 = *(const float4*)(s2 +  4),
           c2 = *(const float4*)(s2 +  8), c3 = *(const float4*)(s2 + 12),
           c4 = *(const float4*)(s2 + 16);

    float4 v0 = fmin4(fmin4(a0, b0), c0);
    float4 v1 = fmin4(fmin4(a1, b1), c1);
    float4 v2 = fmin4(fmin4(a2, b2), c2);
    float4 v3 = fmin4(fmin4(a3, b3), c3);
    float4 v4 = fmin4(fmin4(a4, b4), c4);

    float4 m4 = fmin4(v1, fmin4(v2, v3));
    float common = fminf(fminf(m4.x, m4.y), fminf(m4.z, m4.w));
    float pz = fminf(v0.z, v0.w);
    float sz = fminf(v4.x, v4.y);
    float4 o;
    o.x = fminf(common, fminf(v0.y, pz));
    o.y = fminf(common, fminf(pz, v4.x));
    o.z = fminf(common, fminf(v0.w, sz));
    o.w = fminf(common, fminf(sz, v4.z));

    if (t < 2) {
        float pm7  = fminf(fminf(fminf(v0.x, v0.y), fminf(v0.z, v0.w)),
                           fminf(fminf(v1.x, v1.y), fminf(v1.z, v1.w)));
        float pm8  = fminf(pm7,  v2.x);
        float pm9  = fminf(pm8,  v2.y);
        float pm10 = fminf(pm9,  v2.z);
        float pm11 = fminf(pm10, v2.w);
        float pm12 = fminf(pm11, v3.x);
        float pm13 = fminf(pm12, v3.y);
        float pm14 = fminf(pm13, v3.z);
        if (t == 0) { o.x = pm7;  o.y = pm8;  o.z = pm9;  o.w = pm10; }
        else        { o.x = pm11; o.y = pm12; o.z = pm13; o.w = pm14; }
    } else if (t >= 126) {
        float sm12 = fminf(fminf(fminf(v4.x, v4.y), fminf(v4.z, v4.w)),
                           fminf(fminf(v3.x, v3.y), fminf(v3.z, v3.w)));
        float sm11 = fminf(sm12, v2.w);
        float sm10 = fminf(sm11, v2.z);
        float sm9  = fminf(sm10, v2.y);
        float sm8  = fminf(sm9,  v2.x);
        float sm7  = fminf(sm8,  v1.w);
        float sm6  = fminf(sm7,  v1.z);
        float sm5  = fminf(sm6,  v1.y);
        if (t == 126) { o.x = sm5; o.y = sm6;  o.z = sm7;  o.w = sm8;  }
        else          { o.x = sm9; o.y = sm10; o.z = sm11; o.w = sm12; }
    }

    *(float4*)(hmin + img * CH_STRIDE + row * IMG + 4 * t) = o;
}

// ---------------- Kernel 2: vertical 15-min, van Herk period 16 ------------
// CHANGE vs R4: 2 cols/thread (float2) -> 2x waves (8/CU), VGPR ~halved.
__global__ __launch_bounds__(256)
void vpass(const float* __restrict__ hmin, float* __restrict__ out) {
    int idx = blockIdx.x * 256 + threadIdx.x;   // 16*32*256 = 131,072
    int c   = idx & 255;           // 2-col group
    int ss  = idx >> 8;
    int s   = ss & 31;
    int img = ss >> 5;

    const float* base = hmin + img * CH_STRIDE + 2 * c;
    int r0 = 16 * s - 8;

    float2 A[16], B[16];
    #pragma unroll
    for (int j = 0; j < 16; ++j) {       // rows r0 .. r0+15 (reflect low)
        int r = r0 + j;
        r = r < 0 ? -r : r;
        A[j] = *(const float2*)(base + r * IMG);
    }
    #pragma unroll
    for (int j = 0; j < 16; ++j) {       // rows r0+16 .. r0+31 (reflect high)
        int r = r0 + 16 + j;
        r = r > IMG - 1 ? 2 * (IMG - 1) - r : r;
        B[j] = *(const float2*)(base + r * IMG);
    }

    #pragma unroll
    for (int j = 14; j >= 0; --j) A[j] = fmin2(A[j], A[j + 1]);

    float* ob = out + img * CH_STRIDE + (16 * s) * IMG + 2 * c;
    *(float2*)(ob) = A[1];
    float2 pr = B[0];
    #pragma unroll
    for (int k = 1; k <= 14; ++k) {
        *(float2*)(ob + k * IMG) = fmin2(A[k + 1], pr);
        pr = fmin2(pr, B[k]);
    }
    *(float2*)(ob + 15 * IMG) = pr;
}

// ---------------- Fallback fused kernel (round-3, known-correct) -----------
#define KER    15
#define PAD    7
#define TILE_W 64
#define TILE_H 64
#define SH     (TILE_H + 2 * PAD)
#define SW2    80
#define NTHREADS 512

__device__ __forceinline__ int reflect_idx(int i) {
    i = i < 0 ? -i : i;
    return i > IMG - 1 ? 2 * (IMG - 1) - i : i;
}

__global__ __launch_bounds__(NTHREADS, 8)
void dark_channel_fused(const float* __restrict__ x, float* __restrict__ out) {
    __shared__ float smin[SH][SW2];
    const int tid = threadIdx.x;
    const int bx  = blockIdx.x;
    const int by  = blockIdx.y;
    const int b   = blockIdx.z;
    const int base  = b * 3 * CH_STRIDE;
    const int row0  = by * TILE_H - PAD;
    const int col0a = bx * TILE_W - (PAD + 1);

    #pragma unroll
    for (int it = 0; it < 4; ++it) {
        int idx = tid + it * NTHREADS;
        if (idx < SH * 20) {
            int r  = idx / 20;
            int c4 = idx - r * 20;
            int gr = reflect_idx(row0 + r);
            int gc = col0a + 4 * c4;
            float4 v;
            if (gc >= 0 && gc <= IMG - 4) {
                int off = base + gr * IMG + gc;
                float4 a  = *(const float4*)(x + off);
                float4 bb = *(const float4*)(x + off + CH_STRIDE);
                float4 cc = *(const float4*)(x + off + 2 * CH_STRIDE);
                v = fmin4(fmin4(a, bb), cc);
            } else {
                #pragma unroll
                for (int j = 0; j < 4; ++j) {
                    int g   = reflect_idx(gc + j);
                    int off = base + gr * IMG + g;
                    float m = fminf(fminf(x[off], x[off + CH_STRIDE]), x[off + 2 * CH_STRIDE]);
                    if (j == 0) v.x = m; else if (j == 1) v.y = m;
                    else if (j == 2) v.z = m; else v.w = m;
                }
            }
            *(float4*)&smin[r][4 * c4] = v;
        }
    }
    __syncthreads();

    float4 h0, h1, h2;
    #pragma unroll
    for (int it = 0; it < 3; ++it) {
        int idx = tid + it * NTHREADS;
        if (idx < SH * 16) {
            int r  = idx >> 4;
            int c4 = idx & 15;
            const float* rowp = &smin[r][4 * c4];
            float4 v0 = *(const float4*)(rowp);
            float4 v1 = *(const float4*)(rowp + 4);
            float4 v2 = *(const float4*)(rowp + 8);
            float4 v3 = *(const float4*)(rowp + 12);
            float4 v4 = *(const float4*)(rowp + 16);
            float4 o  = hgroup(v0, v1, v2, v3, v4);
            if (it == 0) h0 = o; else if (it == 1) h1 = o; else h2 = o;
        }
    }
    __syncthreads();

    #pragma unroll
    for (int it = 0; it < 3; ++it) {
        int idx = tid + it * NTHREADS;
        if (idx < SH * 16) {
            int r  = idx >> 4;
            int c4 = idx & 15;
            float4 o = (it == 0) ? h0 : (it == 1) ? h1 : h2;
            *(float4*)&smin[r][4 * c4] = o;
        }
    }
    __syncthreads();

    #pragma unroll
    for (int it = 0; it < 2; ++it) {
        int idx = tid + it * NTHREADS;
        int rg = idx >> 6;
        int c  = idx & 63;
        int rb = rg * 4;
        float w0  = smin[rb +  0][c], w1  = smin[rb +  1][c], w2  = smin[rb +  2][c];
        float w3  = smin[rb +  3][c], w4  = smin[rb +  4][c], w5  = smin[rb +  5][c];
        float w6  = smin[rb +  6][c], w7  = smin[rb +  7][c], w8  = smin[rb +  8][c];
        float w9  = smin[rb +  9][c], w10 = smin[rb + 10][c], w11 = smin[rb + 11][c];
        float w12 = smin[rb + 12][c], w13 = smin[rb + 13][c], w14 = smin[rb + 14][c];
        float w15 = smin[rb + 15][c], w16 = smin[rb + 16][c], w17 = smin[rb + 17][c];
        float ca = fminf(fminf(w3, w4),  fminf(w5, w6));
        float cb = fminf(fminf(w7, w8),  fminf(w9, w10));
        float cc = fminf(fminf(w11, w12), fminf(w13, w14));
        float common = fminf(ca, fminf(cb, cc));
        float p = fminf(w1, w2);
        float s = fminf(w15, w16);
        int obase = b * CH_STRIDE + (by * TILE_H + rb) * IMG + bx * TILE_W + c;
        out[obase]           = fminf(common, fminf(w0, p));
        out[obase + IMG]     = fminf(common, fminf(p, w15));
        out[obase + 2 * IMG] = fminf(common, fminf(w2, s));
        out[obase + 3 * IMG] = fminf(common, fminf(s, w17));
    }
}

extern "C" void kernel_launch(void* const* d_in, const int* in_sizes, int n_in,
                              void* d_out, int out_size, void* d_ws, size_t ws_size,
                              hipStream_t stream) {
    const float* x = (const float*)d_in[0];
    float* out = (float*)d_out;
    const size_t need = (size_t)16 * CH_STRIDE * sizeof(float);  // 16.8 MB
    if (ws_size >= need && d_ws != nullptr) {
        float* hm = (float*)d_ws;
        hpass<<<dim3(16 * 512 * 128 / 256), dim3(256), 0, stream>>>(x, hm);
        vpass<<<dim3(16 * 32 * 256 / 256),  dim3(256), 0, stream>>>(hm, out);
    } else {
        dim3 grid(IMG / TILE_W, IMG / TILE_H, 16);
        dark_channel_fused<<<grid, dim3(NTHREADS), 0, stream>>>(x, out);
    }
}

// Round 8
// 23.573 us; speedup vs baseline: 1.2312x; 1.0575x over previous
//
#include <hip/hip_runtime.h>

#define IMG 512
#define CH_STRIDE (IMG * IMG)   // 262144

__device__ __forceinline__ float4 fmin4(float4 a, float4 b) {
    float4 r;
    r.x = fminf(a.x, b.x); r.y = fminf(a.y, b.y);
    r.z = fminf(a.z, b.z); r.w = fminf(a.w, b.w);
    return r;
}

__device__ __forceinline__ float2 fmin2(float2 a, float2 b) {
    float2 r;
    r.x = fminf(a.x, b.x); r.y = fminf(a.y, b.y);
    return r;
}

// hgroup kept for the fallback kernel
__device__ __forceinline__ float4 hgroup(float4 u0, float4 u1, float4 u2,
                                         float4 u3, float4 u4) {
    float4 m4 = fmin4(u1, fmin4(u2, u3));
    float common = fminf(fminf(m4.x, m4.y), fminf(m4.z, m4.w));
    float pz = fminf(u0.z, u0.w);
    float sz = fminf(u4.x, u4.y);
    float4 o;
    o.x = fminf(common, fminf(u0.y, pz));
    o.y = fminf(common, fminf(pz, u4.x));
    o.z = fminf(common, fminf(u0.w, sz));
    o.w = fminf(common, fminf(sz, u4.z));
    return o;
}

// ---------------- Kernel 1: channel-min + horizontal 15-min ----------------
// Wave-parallel van Herk: 1 wave = 1 row (64 lanes x 8 cols). Each lane:
// 6 unique float4 loads (no overlap), P/S mins, 14 shuffles, 2 stores.
// Reflection at lanes 0/63 is free: shfl returns own S/P which is a subset
// of the reflected window (window-coverage proven exact).
__global__ __launch_bounds__(256)
void hpass(const float* __restrict__ x, float* __restrict__ hmin) {
    int gid  = blockIdx.x * 4 + (threadIdx.x >> 6);  // global row id, 0..8191
    int lane = threadIdx.x & 63;
    int img  = gid >> 9;
    int row  = gid & 511;

    const float* p = x + img * 3 * CH_STRIDE + row * IMG + 8 * lane;
    float4 a0 = *(const float4*)(p),                  a1 = *(const float4*)(p + 4);
    float4 b0 = *(const float4*)(p + CH_STRIDE),      b1 = *(const float4*)(p + CH_STRIDE + 4);
    float4 c0 = *(const float4*)(p + 2 * CH_STRIDE),  c1 = *(const float4*)(p + 2 * CH_STRIDE + 4);
    float4 v0 = fmin4(fmin4(a0, b0), c0);   // cols 8L .. 8L+3 (channel-min)
    float4 v1 = fmin4(fmin4(a1, b1), c1);   // cols 8L+4 .. 8L+7

    float w0 = v0.x, w1 = v0.y, w2 = v0.z, w3 = v0.w;
    float w4 = v1.x, w5 = v1.y, w6 = v1.z, w7 = v1.w;

    // prefix mins P[i] = min(w0..wi), suffix mins S[i] = min(wi..w7)
    float P1 = fminf(w0, w1), P2 = fminf(P1, w2), P3 = fminf(P2, w3),
          P4 = fminf(P3, w4), P5 = fminf(P4, w5), P6 = fminf(P5, w6),
          M  = fminf(P6, w7);                 // M = P7 = min of all 8
    float S6 = fminf(w7, w6), S5 = fminf(S6, w5), S4 = fminf(S5, w4),
          S3 = fminf(S4, w3), S2 = fminf(S3, w2), S1 = fminf(S2, w1);

    // left neighbor's suffixes, right neighbor's prefixes
    float SL1 = __shfl_up(S1, 1), SL2 = __shfl_up(S2, 1), SL3 = __shfl_up(S3, 1),
          SL4 = __shfl_up(S4, 1), SL5 = __shfl_up(S5, 1), SL6 = __shfl_up(S6, 1),
          SL7 = __shfl_up(w7, 1);
    float PR0 = __shfl_down(w0, 1), PR1 = __shfl_down(P1, 1), PR2 = __shfl_down(P2, 1),
          PR3 = __shfl_down(P3, 1), PR4 = __shfl_down(P4, 1), PR5 = __shfl_down(P5, 1),
          PR6 = __shfl_down(P6, 1);

    // out[k] = min(SL[k+1], M, PR[k-1])   (k-th of this lane's 8 output cols)
    float4 o0, o1;
    o0.x = fminf(SL1, M);
    o0.y = fminf(SL2, fminf(M, PR0));
    o0.z = fminf(SL3, fminf(M, PR1));
    o0.w = fminf(SL4, fminf(M, PR2));
    o1.x = fminf(SL5, fminf(M, PR3));
    o1.y = fminf(SL6, fminf(M, PR4));
    o1.z = fminf(SL7, fminf(M, PR5));
    o1.w = fminf(M, PR6);

    float* op = hmin + img * CH_STRIDE + row * IMG + 8 * lane;
    *(float4*)(op)     = o0;
    *(float4*)(op + 4) = o1;
}

// ---------------- Kernel 2: vertical 15-min, van Herk period 16 ------------
// (Round-7 float2 version — measured equal-best; unchanged.)
__global__ __launch_bounds__(256)
void vpass(const float* __restrict__ hmin, float* __restrict__ out) {
    int idx = blockIdx.x * 256 + threadIdx.x;   // 16*32*256 = 131,072
    int c   = idx & 255;           // 2-col group
    int ss  = idx >> 8;
    int s   = ss & 31;
    int img = ss >> 5;

    const float* base = hmin + img * CH_STRIDE + 2 * c;
    int r0 = 16 * s - 8;

    float2 A[16], B[16];
    #pragma unroll
    for (int j = 0; j < 16; ++j) {       // rows r0 .. r0+15 (reflect low)
        int r = r0 + j;
        r = r < 0 ? -r : r;
        A[j] = *(const float2*)(base + r * IMG);
    }
    #pragma unroll
    for (int j = 0; j < 16; ++j) {       // rows r0+16 .. r0+31 (reflect high)
        int r = r0 + 16 + j;
        r = r > IMG - 1 ? 2 * (IMG - 1) - r : r;
        B[j] = *(const float2*)(base + r * IMG);
    }

    #pragma unroll
    for (int j = 14; j >= 0; --j) A[j] = fmin2(A[j], A[j + 1]);

    float* ob = out + img * CH_STRIDE + (16 * s) * IMG + 2 * c;
    *(float2*)(ob) = A[1];
    float2 pr = B[0];
    #pragma unroll
    for (int k = 1; k <= 14; ++k) {
        *(float2*)(ob + k * IMG) = fmin2(A[k + 1], pr);
        pr = fmin2(pr, B[k]);
    }
    *(float2*)(ob + 15 * IMG) = pr;
}

// ---------------- Fallback fused kernel (round-3, known-correct) -----------
#define KER    15
#define PAD    7
#define TILE_W 64
#define TILE_H 64
#define SH     (TILE_H + 2 * PAD)
#define SW2    80
#define NTHREADS 512

__device__ __forceinline__ int reflect_idx(int i) {
    i = i < 0 ? -i : i;
    return i > IMG - 1 ? 2 * (IMG - 1) - i : i;
}

__global__ __launch_bounds__(NTHREADS, 8)
void dark_channel_fused(const float* __restrict__ x, float* __restrict__ out) {
    __shared__ float smin[SH][SW2];
    const int tid = threadIdx.x;
    const int bx  = blockIdx.x;
    const int by  = blockIdx.y;
    const int b   = blockIdx.z;
    const int base  = b * 3 * CH_STRIDE;
    const int row0  = by * TILE_H - PAD;
    const int col0a = bx * TILE_W - (PAD + 1);

    #pragma unroll
    for (int it = 0; it < 4; ++it) {
        int idx = tid + it * NTHREADS;
        if (idx < SH * 20) {
            int r  = idx / 20;
            int c4 = idx - r * 20;
            int gr = reflect_idx(row0 + r);
            int gc = col0a + 4 * c4;
            float4 v;
            if (gc >= 0 && gc <= IMG - 4) {
                int off = base + gr * IMG + gc;
                float4 a  = *(const float4*)(x + off);
                float4 bb = *(const float4*)(x + off + CH_STRIDE);
                float4 cc = *(const float4*)(x + off + 2 * CH_STRIDE);
                v = fmin4(fmin4(a, bb), cc);
            } else {
                #pragma unroll
                for (int j = 0; j < 4; ++j) {
                    int g   = reflect_idx(gc + j);
                    int off = base + gr * IMG + g;
                    float m = fminf(fminf(x[off], x[off + CH_STRIDE]), x[off + 2 * CH_STRIDE]);
                    if (j == 0) v.x = m; else if (j == 1) v.y = m;
                    else if (j == 2) v.z = m; else v.w = m;
                }
            }
            *(float4*)&smin[r][4 * c4] = v;
        }
    }
    __syncthreads();

    float4 h0, h1, h2;
    #pragma unroll
    for (int it = 0; it < 3; ++it) {
        int idx = tid + it * NTHREADS;
        if (idx < SH * 16) {
            int r  = idx >> 4;
            int c4 = idx & 15;
            const float* rowp = &smin[r][4 * c4];
            float4 v0 = *(const float4*)(rowp);
            float4 v1 = *(const float4*)(rowp + 4);
            float4 v2 = *(const float4*)(rowp + 8);
            float4 v3 = *(const float4*)(rowp + 12);
            float4 v4 = *(const float4*)(rowp + 16);
            float4 o  = hgroup(v0, v1, v2, v3, v4);
            if (it == 0) h0 = o; else if (it == 1) h1 = o; else h2 = o;
        }
    }
    __syncthreads();

    #pragma unroll
    for (int it = 0; it < 3; ++it) {
        int idx = tid + it * NTHREADS;
        if (idx < SH * 16) {
            int r  = idx >> 4;
            int c4 = idx & 15;
            float4 o = (it == 0) ? h0 : (it == 1) ? h1 : h2;
            *(float4*)&smin[r][4 * c4] = o;
        }
    }
    __syncthreads();

    #pragma unroll
    for (int it = 0; it < 2; ++it) {
        int idx = tid + it * NTHREADS;
        int rg = idx >> 6;
        int c  = idx & 63;
        int rb = rg * 4;
        float w0  = smin[rb +  0][c], w1  = smin[rb +  1][c], w2  = smin[rb +  2][c];
        float w3  = smin[rb +  3][c], w4  = smin[rb +  4][c], w5  = smin[rb +  5][c];
        float w6  = smin[rb +  6][c], w7  = smin[rb +  7][c], w8  = smin[rb +  8][c];
        float w9  = smin[rb +  9][c], w10 = smin[rb + 10][c], w11 = smin[rb + 11][c];
        float w12 = smin[rb + 12][c], w13 = smin[rb + 13][c], w14 = smin[rb + 14][c];
        float w15 = smin[rb + 15][c], w16 = smin[rb + 16][c], w17 = smin[rb + 17][c];
        float ca = fminf(fminf(w3, w4),  fminf(w5, w6));
        float cb = fminf(fminf(w7, w8),  fminf(w9, w10));
        float cc = fminf(fminf(w11, w12), fminf(w13, w14));
        float common = fminf(ca, fminf(cb, cc));
        float p = fminf(w1, w2);
        float s = fminf(w15, w16);
        int obase = b * CH_STRIDE + (by * TILE_H + rb) * IMG + bx * TILE_W + c;
        out[obase]           = fminf(common, fminf(w0, p));
        out[obase + IMG]     = fminf(common, fminf(p, w15));
        out[obase + 2 * IMG] = fminf(common, fminf(w2, s));
        out[obase + 3 * IMG] = fminf(common, fminf(s, w17));
    }
}

extern "C" void kernel_launch(void* const* d_in, const int* in_sizes, int n_in,
                              void* d_out, int out_size, void* d_ws, size_t ws_size,
                              hipStream_t stream) {
    const float* x = (const float*)d_in[0];
    float* out = (float*)d_out;
    const size_t need = (size_t)16 * CH_STRIDE * sizeof(float);  // 16.8 MB
    if (ws_size >= need && d_ws != nullptr) {
        float* hm = (float*)d_ws;
        hpass<<<dim3(16 * 512 / 4), dim3(256), 0, stream>>>(x, hm);       // 2048 blocks
        vpass<<<dim3(16 * 32 * 256 / 256), dim3(256), 0, stream>>>(hm, out);
    } else {
        dim3 grid(IMG / TILE_W, IMG / TILE_H, 16);
        dark_channel_fused<<<grid, dim3(NTHREADS), 0, stream>>>(x, out);
    }
}

// Round 9
// 19.028 us; speedup vs baseline: 1.5254x; 1.2389x over previous
//
#include <hip/hip_runtime.h>

#define IMG 512
#define CH_STRIDE (IMG * IMG)   // 262144
#define STRIP 32
#define HR    46                // STRIP + 14 halo rows

typedef __attribute__((ext_vector_type(8))) _Float16 half8;
typedef __attribute__((ext_vector_type(4))) _Float16 half4;

__device__ __forceinline__ float4 fmin4(float4 a, float4 b) {
    float4 r;
    r.x = fminf(a.x, b.x); r.y = fminf(a.y, b.y);
    r.z = fminf(a.z, b.z); r.w = fminf(a.w, b.w);
    return r;
}

// ---------------- Fused: channel-min + h-min (wave van Herk) -> LDS fp16;
// ---------------- barrier; v-min -> out. One kernel, no intermediate in HBM.
__global__ __launch_bounds__(512)
void dark_fused(const float* __restrict__ x, float* __restrict__ out) {
    __shared__ _Float16 hm[HR][IMG];   // 47104 B

    const int tid   = threadIdx.x;
    const int wave  = tid >> 6;        // 0..7
    const int lane  = tid & 63;
    const int strip = blockIdx.x;      // 0..15
    const int img   = blockIdx.y;      // 0..15
    const int r0    = strip * STRIP - 7;

    const float* xb = x + img * 3 * CH_STRIDE;

    // ---- phase 1: 46 halo rows, one row per wave-iteration ----
    // (R8-verified wave van Herk: 8 cols/lane, P/S mins, 14 shuffles.)
    for (int j = wave; j < HR; j += 8) {
        int gr = r0 + j;
        gr = gr < 0 ? -gr : (gr > IMG - 1 ? 2 * (IMG - 1) - gr : gr);
        const float* p = xb + gr * IMG + 8 * lane;

        float4 a0 = *(const float4*)(p),                 a1 = *(const float4*)(p + 4);
        float4 b0 = *(const float4*)(p + CH_STRIDE),     b1 = *(const float4*)(p + CH_STRIDE + 4);
        float4 c0 = *(const float4*)(p + 2 * CH_STRIDE), c1 = *(const float4*)(p + 2 * CH_STRIDE + 4);
        float4 v0 = fmin4(fmin4(a0, b0), c0);
        float4 v1 = fmin4(fmin4(a1, b1), c1);

        float w0 = v0.x, w1 = v0.y, w2 = v0.z, w3 = v0.w;
        float w4 = v1.x, w5 = v1.y, w6 = v1.z, w7 = v1.w;

        float P1 = fminf(w0, w1), P2 = fminf(P1, w2), P3 = fminf(P2, w3),
              P4 = fminf(P3, w4), P5 = fminf(P4, w5), P6 = fminf(P5, w6),
              M  = fminf(P6, w7);
        float S6 = fminf(w7, w6), S5 = fminf(S6, w5), S4 = fminf(S5, w4),
              S3 = fminf(S4, w3), S2 = fminf(S3, w2), S1 = fminf(S2, w1);

        float SL1 = __shfl_up(S1, 1), SL2 = __shfl_up(S2, 1), SL3 = __shfl_up(S3, 1),
              SL4 = __shfl_up(S4, 1), SL5 = __shfl_up(S5, 1), SL6 = __shfl_up(S6, 1),
              SL7 = __shfl_up(w7, 1);
        float PR0 = __shfl_down(w0, 1), PR1 = __shfl_down(P1, 1), PR2 = __shfl_down(P2, 1),
              PR3 = __shfl_down(P3, 1), PR4 = __shfl_down(P4, 1), PR5 = __shfl_down(P5, 1),
              PR6 = __shfl_down(P6, 1);

        // out[k] = min(SL[k+1], M, PR[k-1]); lanes 0/63 self-shfl = exact reflect
        half8 hv;
        hv[0] = (_Float16)fminf(SL1, M);
        hv[1] = (_Float16)fminf(SL2, fminf(M, PR0));
        hv[2] = (_Float16)fminf(SL3, fminf(M, PR1));
        hv[3] = (_Float16)fminf(SL4, fminf(M, PR2));
        hv[4] = (_Float16)fminf(SL5, fminf(M, PR3));
        hv[5] = (_Float16)fminf(SL6, fminf(M, PR4));
        hv[6] = (_Float16)fminf(SL7, fminf(M, PR5));
        hv[7] = (_Float16)fminf(M, PR6);
        *(half8*)&hm[j][8 * lane] = hv;
    }
    __syncthreads();

    // ---- phase 2: vertical 15-min from LDS ----
    // thread -> 4 cols (c4) x 8 out rows (rg*8 ..); hm rows jb .. jb+21
    const int c4 = tid & 127;
    const int rg = tid >> 7;          // 0..3
    const int jb = rg * 8;

    float4 w[22];
    #pragma unroll
    for (int i = 0; i < 22; ++i) {
        half4 h = *(half4*)&hm[jb + i][4 * c4];
        w[i] = make_float4((float)h[0], (float)h[1], (float)h[2], (float)h[3]);
    }

    // suffix min over w[0..14]: w[i] = min(orig w[i..14])
    #pragma unroll
    for (int i = 13; i >= 0; --i) w[i] = fmin4(w[i], w[i + 1]);

    float* ob = out + img * CH_STRIDE + (strip * STRIP + jb) * IMG + 4 * c4;
    *(float4*)(ob) = w[0];
    float4 pr = w[15];
    #pragma unroll
    for (int k = 1; k < 8; ++k) {
        *(float4*)(ob + k * IMG) = fmin4(w[k], pr);
        if (k < 7) pr = fmin4(pr, w[15 + k]);
    }
}

extern "C" void kernel_launch(void* const* d_in, const int* in_sizes, int n_in,
                              void* d_out, int out_size, void* d_ws, size_t ws_size,
                              hipStream_t stream) {
    const float* x = (const float*)d_in[0];
    float* out = (float*)d_out;
    dim3 grid(IMG / STRIP, 16);   // 16 strips x 16 images = 256 blocks
    dark_fused<<<grid, dim3(512), 0, stream>>>(x, out);
}

// Round 10
// 18.412 us; speedup vs baseline: 1.5764x; 1.0334x over previous
//
#include <hip/hip_runtime.h>

#define IMG 512
#define CH_STRIDE (IMG * IMG)   // 262144
#define STRIP 32
#define HR    46                // STRIP + 14 halo rows
#define NT    1024

typedef __attribute__((ext_vector_type(8))) _Float16 half8;
typedef __attribute__((ext_vector_type(4))) _Float16 half4;

__device__ __forceinline__ float4 fmin4(float4 a, float4 b) {
    float4 r;
    r.x = fminf(a.x, b.x); r.y = fminf(a.y, b.y);
    r.z = fminf(a.z, b.z); r.w = fminf(a.w, b.w);
    return r;
}

// Fused: channel-min + h-min (wave van Herk) -> LDS fp16; barrier; v-min -> out.
// R10: 1024-thread blocks (16 waves/CU) + XCD-aware block swizzle.
__global__ __launch_bounds__(NT)
void dark_fused(const float* __restrict__ x, float* __restrict__ out) {
    __shared__ _Float16 hm[HR][IMG];   // 47104 B

    const int tid  = threadIdx.x;
    const int wave = tid >> 6;         // 0..15
    const int lane = tid & 63;

    // XCD swizzle: all 16 strips of an image share one XCD (L2 halo reuse).
    const int bid   = blockIdx.x;          // 0..255
    const int img   = 2 * (bid & 7) + (bid >> 7);
    const int strip = (bid >> 3) & 15;
    const int r0    = strip * STRIP - 7;

    const float* xb = x + img * 3 * CH_STRIDE;

    // ---- phase 1: 46 halo rows, one row per wave-iteration ----
    // (R8-verified wave van Herk: 8 cols/lane, P/S mins, 14 shuffles.)
    for (int j = wave; j < HR; j += 16) {
        int gr = r0 + j;
        gr = gr < 0 ? -gr : (gr > IMG - 1 ? 2 * (IMG - 1) - gr : gr);
        const float* p = xb + gr * IMG + 8 * lane;

        float4 a0 = *(const float4*)(p),                 a1 = *(const float4*)(p + 4);
        float4 b0 = *(const float4*)(p + CH_STRIDE),     b1 = *(const float4*)(p + CH_STRIDE + 4);
        float4 c0 = *(const float4*)(p + 2 * CH_STRIDE), c1 = *(const float4*)(p + 2 * CH_STRIDE + 4);
        float4 v0 = fmin4(fmin4(a0, b0), c0);
        float4 v1 = fmin4(fmin4(a1, b1), c1);

        float w0 = v0.x, w1 = v0.y, w2 = v0.z, w3 = v0.w;
        float w4 = v1.x, w5 = v1.y, w6 = v1.z, w7 = v1.w;

        float P1 = fminf(w0, w1), P2 = fminf(P1, w2), P3 = fminf(P2, w3),
              P4 = fminf(P3, w4), P5 = fminf(P4, w5), P6 = fminf(P5, w6),
              M  = fminf(P6, w7);
        float S6 = fminf(w7, w6), S5 = fminf(S6, w5), S4 = fminf(S5, w4),
              S3 = fminf(S4, w3), S2 = fminf(S3, w2), S1 = fminf(S2, w1);

        float SL1 = __shfl_up(S1, 1), SL2 = __shfl_up(S2, 1), SL3 = __shfl_up(S3, 1),
              SL4 = __shfl_up(S4, 1), SL5 = __shfl_up(S5, 1), SL6 = __shfl_up(S6, 1),
              SL7 = __shfl_up(w7, 1);
        float PR0 = __shfl_down(w0, 1), PR1 = __shfl_down(P1, 1), PR2 = __shfl_down(P2, 1),
              PR3 = __shfl_down(P3, 1), PR4 = __shfl_down(P4, 1), PR5 = __shfl_down(P5, 1),
              PR6 = __shfl_down(P6, 1);

        // out[k] = min(SL[k+1], M, PR[k-1]); lanes 0/63 self-shfl = exact reflect
        half8 hv;
        hv[0] = (_Float16)fminf(SL1, M);
        hv[1] = (_Float16)fminf(SL2, fminf(M, PR0));
        hv[2] = (_Float16)fminf(SL3, fminf(M, PR1));
        hv[3] = (_Float16)fminf(SL4, fminf(M, PR2));
        hv[4] = (_Float16)fminf(SL5, fminf(M, PR3));
        hv[5] = (_Float16)fminf(SL6, fminf(M, PR4));
        hv[6] = (_Float16)fminf(SL7, fminf(M, PR5));
        hv[7] = (_Float16)fminf(M, PR6);
        *(half8*)&hm[j][8 * lane] = hv;
    }
    __syncthreads();

    // ---- phase 2: vertical 15-min from LDS ----
    // thread -> 4 cols (c4) x 4 out rows (jb..jb+3); hm rows jb .. jb+17
    const int c4 = tid & 127;
    const int jb = (tid >> 7) * 4;    // 0,4,...,28

    float4 w[18];
    #pragma unroll
    for (int i = 0; i < 18; ++i) {
        half4 h = *(half4*)&hm[jb + i][4 * c4];
        w[i] = make_float4((float)h[0], (float)h[1], (float)h[2], (float)h[3]);
    }

    float4 ca = fmin4(fmin4(w[3],  w[4]),  fmin4(w[5],  w[6]));
    float4 cb = fmin4(fmin4(w[7],  w[8]),  fmin4(w[9],  w[10]));
    float4 cc = fmin4(fmin4(w[11], w[12]), fmin4(w[13], w[14]));
    float4 common = fmin4(ca, fmin4(cb, cc));
    float4 p01 = fmin4(w[1], w[2]);
    float4 s01 = fmin4(w[15], w[16]);

    float* ob = out + img * CH_STRIDE + (strip * STRIP + jb) * IMG + 4 * c4;
    *(float4*)(ob)           = fmin4(fmin4(w[0], p01), common);
    *(float4*)(ob + IMG)     = fmin4(fmin4(p01, w[15]), common);
    *(float4*)(ob + 2 * IMG) = fmin4(fmin4(w[2], s01), common);
    *(float4*)(ob + 3 * IMG) = fmin4(fmin4(s01, w[17]), common);
}

extern "C" void kernel_launch(void* const* d_in, const int* in_sizes, int n_in,
                              void* d_out, int out_size, void* d_ws, size_t ws_size,
                              hipStream_t stream) {
    const float* x = (const float*)d_in[0];
    float* out = (float*)d_out;
    dark_fused<<<dim3(256), dim3(NT), 0, stream>>>(x, out);
}